// Round 1
// baseline (587.921 us; speedup 1.0000x reference)
//
#include <hip/hip_runtime.h>
#include <hip/hip_bf16.h>
#include <cstdint>
#include <cstddef>

typedef unsigned short u16;
typedef unsigned int u32;
typedef __attribute__((ext_vector_type(8))) short short8;
typedef __attribute__((ext_vector_type(4))) float floatx4;

#define DD 1024
#define NE 8

// 16-byte async global->LDS copy (gfx950). LDS dest must be wave-uniform base + lane*16;
// global source address is per-lane (gather OK).
#define GLOAD_LDS16(G, L)                                               \
  __builtin_amdgcn_global_load_lds(                                     \
      (const __attribute__((address_space(1))) void*)(G),               \
      (__attribute__((address_space(3))) void*)(L), 16, 0, 0)

__device__ __forceinline__ u16 f2bf(float f) {
  union { __hip_bfloat16 h; u16 u; } cv;
  cv.h = __float2bfloat16(f);
  return cv.u;
}

__device__ __forceinline__ float2 bf2f2(u32 u) {
  union { u32 v; float f; } lo, hi;
  lo.v = u << 16; hi.v = u & 0xffff0000u;
  float2 r; r.x = lo.f; r.y = hi.f; return r;
}

// ---------------- router: fp32 logits, top-2, softmax weights; emits x in bf16 ----------------
__global__ __launch_bounds__(256) void router_kernel(
    const float* __restrict__ x, const float* __restrict__ rw,
    const float* __restrict__ rb, int2* __restrict__ experts,
    float2* __restrict__ wts, u16* __restrict__ xbf, int T) {
  const int wave = threadIdx.x >> 6;
  const int lane = threadIdx.x & 63;
  const int t = blockIdx.x * 4 + wave;
  if (t >= T) return;
  const float* xr = x + (size_t)t * DD;
  float acc[NE] = {0.f, 0.f, 0.f, 0.f, 0.f, 0.f, 0.f, 0.f};
#pragma unroll
  for (int i = 0; i < 16; i++) {
    const int idx = lane + i * 64;
    const float xv = xr[idx];
    xbf[(size_t)t * DD + idx] = f2bf(xv);
    const float4* r4 = (const float4*)(rw + (size_t)idx * NE);
    float4 a = r4[0], b = r4[1];
    acc[0] += xv * a.x; acc[1] += xv * a.y; acc[2] += xv * a.z; acc[3] += xv * a.w;
    acc[4] += xv * b.x; acc[5] += xv * b.y; acc[6] += xv * b.z; acc[7] += xv * b.w;
  }
#pragma unroll
  for (int s = 1; s < 64; s <<= 1)
#pragma unroll
    for (int e = 0; e < NE; e++)
      acc[e] += __shfl_xor(acc[e], s);
  if (lane == 0) {
    float lg[NE];
#pragma unroll
    for (int e = 0; e < NE; e++) lg[e] = acc[e] + rb[e];
    float l0 = lg[0]; int i0 = 0;
#pragma unroll
    for (int e = 1; e < NE; e++) if (lg[e] > l0) { l0 = lg[e]; i0 = e; }
    float l1 = -3.4e38f; int i1 = 0;
#pragma unroll
    for (int e = 0; e < NE; e++) {
      if (e == i0) continue;
      if (lg[e] > l1) { l1 = lg[e]; i1 = e; }
    }
    const float w0 = 1.f / (1.f + expf(l1 - l0));
    experts[t] = make_int2(i0, i1);
    wts[t] = make_float2(w0, 1.f - w0);
  }
}

// ---------------- count tokens per expert ----------------
__global__ __launch_bounds__(256) void count_kernel(
    const int2* __restrict__ experts, int* __restrict__ counts, int T) {
  __shared__ int lc[NE];
  if (threadIdx.x < NE) lc[threadIdx.x] = 0;
  __syncthreads();
  const int t = blockIdx.x * 256 + threadIdx.x;
  if (t < T) {
    int2 e = experts[t];
    atomicAdd(&lc[e.x], 1);
    atomicAdd(&lc[e.y], 1);
  }
  __syncthreads();
  if (threadIdx.x < NE && lc[threadIdx.x] > 0)
    atomicAdd(&counts[threadIdx.x], lc[threadIdx.x]);
}

__global__ void offsets_kernel(const int* __restrict__ counts, int* __restrict__ offsets) {
  int s = 0;
  for (int e = 0; e < NE; e++) { offsets[e] = s; s += counts[e]; }
}

// ---------------- scatter: compact expert groups + inverse map (slots per token) ----------------
__global__ __launch_bounds__(256) void scatter_kernel(
    const int2* __restrict__ experts, const int* __restrict__ offsets,
    int* __restrict__ cursors, int* __restrict__ tok_id,
    int2* __restrict__ slots, int T) {
  __shared__ int lc[NE], lb[NE];
  if (threadIdx.x < NE) lc[threadIdx.x] = 0;
  __syncthreads();
  const int t = blockIdx.x * 256 + threadIdx.x;
  int2 e = make_int2(0, 0);
  int p0 = 0, p1 = 0;
  if (t < T) {
    e = experts[t];
    p0 = atomicAdd(&lc[e.x], 1);
    p1 = atomicAdd(&lc[e.y], 1);
  }
  __syncthreads();
  if (threadIdx.x < NE) lb[threadIdx.x] = atomicAdd(&cursors[threadIdx.x], lc[threadIdx.x]);
  __syncthreads();
  if (t < T) {
    const int s0 = offsets[e.x] + lb[e.x] + p0;
    const int s1 = offsets[e.y] + lb[e.y] + p1;
    tok_id[s0] = t;
    tok_id[s1] = t;
    slots[t] = make_int2(s0, s1);
  }
}

// ---------------- weight transpose + fp32->bf16 convert ----------------
// Wgu: [e][nc][k], nc = ((n>>3)<<4) | (which<<3) | (n&7); Wd: [e][n][k]
__global__ __launch_bounds__(256) void convert_kernel(
    const float* __restrict__ wg, const float* __restrict__ wu,
    const float* __restrict__ wd, u16* __restrict__ Wgu, u16* __restrict__ Wd) {
  const int z = blockIdx.z;        // mat*8 + e
  const int mat = z >> 3;
  const int e = z & 7;
  const float* src = (mat == 0 ? wg : (mat == 1 ? wu : wd)) + (size_t)e * DD * DD;
  __shared__ float tile[64][65];
  const int k0 = blockIdx.y * 64, n0 = blockIdx.x * 64;
  const int tx = threadIdx.x & 63, ty = threadIdx.x >> 6;
#pragma unroll
  for (int i = 0; i < 16; i++) {
    const int kk = i * 4 + ty;
    tile[kk][tx] = src[(size_t)(k0 + kk) * DD + n0 + tx];
  }
  __syncthreads();
#pragma unroll
  for (int i = 0; i < 16; i++) {
    const int nn = i * 4 + ty;
    const int n = n0 + nn;
    const u16 h = f2bf(tile[tx][nn]);   // = src[k0+tx][n]
    if (mat == 2) {
      Wd[((size_t)e * DD + n) * DD + k0 + tx] = h;
    } else {
      const int nc = ((n >> 3) << 4) | (mat << 3) | (n & 7);
      Wgu[((size_t)e * 2048 + nc) * DD + k0 + tx] = h;
    }
  }
}

// ======================================================================
// 256x256-tile grouped GEMM engine, BK=32, 8 waves, 4-deep LDS ring with
// counted vmcnt (T3+T4), XOR-swizzled LDS (T2), setprio around MFMA (T5).
//
// Ring discipline (per wave, 4 global_load_lds per tile-group):
//   prologue: issue L0,L1,L2; vmcnt(8) -> L0 done; barrier.
//   iter t (t<29): issue L(t+3) into buf[(t+3)&3] (= buf[(t-1)&3], whose
//     readers all left at the barrier ending iter t-1); compute buf[t&3];
//     vmcnt(8) -> own L(t+1) done; barrier -> ALL waves' L(t+1) done.
//   tail drains 4 -> 0. One barrier per tile; vmcnt never 0 in steady state.
// ======================================================================

#define GEMM256_LOOP()                                                  \
  STAGE(0); STAGE(1); STAGE(2);                                         \
  asm volatile("s_waitcnt vmcnt(8)" ::: "memory");                      \
  __builtin_amdgcn_s_barrier();                                         \
  asm volatile("" ::: "memory");                                        \
  _Pragma("unroll 1")                                                   \
  for (int kt = 0; kt < 29; ++kt) {                                     \
    STAGE((kt + 3) & 3);                                                \
    COMPUTE((kt & 3) * 8192);                                           \
    asm volatile("s_waitcnt vmcnt(8)" ::: "memory");                    \
    __builtin_amdgcn_s_barrier();                                       \
    asm volatile("" ::: "memory");                                      \
  }                                                                     \
  COMPUTE(1 * 8192);                                                    \
  asm volatile("s_waitcnt vmcnt(4)" ::: "memory");                      \
  __builtin_amdgcn_s_barrier();                                         \
  asm volatile("" ::: "memory");                                        \
  COMPUTE(2 * 8192);                                                    \
  asm volatile("s_waitcnt vmcnt(0)" ::: "memory");                      \
  __builtin_amdgcn_s_barrier();                                         \
  asm volatile("" ::: "memory");                                        \
  COMPUTE(3 * 8192);

#define STAGE(BUF)                                                      \
  {                                                                     \
    GLOAD_LDS16(sA0, &As[(BUF) * 8192 + t * 8]);                        \
    GLOAD_LDS16(sA1, &As[(BUF) * 8192 + 4096 + t * 8]);                 \
    GLOAD_LDS16(sB0, &Bs[(BUF) * 8192 + t * 8]);                        \
    GLOAD_LDS16(sB1, &Bs[(BUF) * 8192 + 4096 + t * 8]);                 \
    sA0 += 32; sA1 += 32; sB0 += 32; sB1 += 32;                         \
  }

#define COMPUTE(BUFO)                                                   \
  {                                                                     \
    short8 a[8], b[4];                                                  \
    _Pragma("unroll")                                                   \
    for (int i = 0; i < 8; i++)                                         \
      a[i] = *(const short8*)&As[(BUFO) + offA + i * 512];              \
    _Pragma("unroll")                                                   \
    for (int j = 0; j < 4; j++)                                         \
      b[j] = *(const short8*)&Bs[(BUFO) + offB + j * 512];              \
    __builtin_amdgcn_s_setprio(1);                                      \
    _Pragma("unroll")                                                   \
    for (int i = 0; i < 8; i++)                                         \
      _Pragma("unroll")                                                 \
      for (int j = 0; j < 4; j++)                                       \
        acc[i][j] = __builtin_amdgcn_mfma_f32_16x16x32_bf16(            \
            a[i], b[j], acc[i][j], 0, 0, 0);                            \
    __builtin_amdgcn_s_setprio(0);                                      \
  }

// ---------------- grouped GEMM 1: H = silu(x@Wg)*(x@Wu) ----------------
__global__ __launch_bounds__(512, 2) void gateup_kernel(
    const u16* __restrict__ xbf, const u16* __restrict__ Wgu,
    const int* __restrict__ tok_id, const int* __restrict__ offsets,
    const int* __restrict__ counts, u16* __restrict__ H) {
  const int e = blockIdx.z;
  const int cnt = counts[e];
  const int m0 = blockIdx.y * 256;
  if (m0 >= cnt) return;
  const int off = offsets[e];
  const int n0 = blockIdx.x * 256;

  __shared__ u16 As[4 * 8192];   // 4 bufs x [256 rows][32 k], 64 KB
  __shared__ u16 Bs[4 * 8192];   // 64 KB

  const int t = threadIdx.x;     // 0..511
  const int lane = t & 63;
  const int wave = t >> 6;       // 0..7
  const int wm = (wave >> 2) * 128;   // 2 M-waves
  const int wn = (wave & 3) * 64;     // 4 N-waves
  const int r16 = lane & 15;
  const int quad = lane >> 4;
  // LDS row = 64B = 4x16B chunks; chunk stored at pos = chunk ^ ((row>>1)&3).
  // Read base rows (wm|wn + i*16 + r16): (row>>1)&3 == (r16>>1)&3 for all i.
  const int swz = quad ^ ((r16 >> 1) & 3);
  const int offA = (wm + r16) * 32 + swz * 8;
  const int offB = (wn + r16) * 32 + swz * 8;

  // staging: thread covers LDS rows (t>>2) and (t>>2)+128, chunk pos t&3.
  const int drow = t >> 2;
  const int dpos = t & 3;
  const int c8 = (dpos ^ ((drow >> 1) & 3)) * 8;   // same for row and row+128
  int r0 = m0 + drow;       if (r0 > cnt - 1) r0 = cnt - 1;
  int r1 = m0 + drow + 128; if (r1 > cnt - 1) r1 = cnt - 1;
  const u16* sA0 = xbf + (size_t)tok_id[off + r0] * DD + c8;
  const u16* sA1 = xbf + (size_t)tok_id[off + r1] * DD + c8;
  const u16* bbase = Wgu + ((size_t)e * 2048 + n0) * DD + c8;
  const u16* sB0 = bbase + (size_t)drow * DD;
  const u16* sB1 = bbase + (size_t)(drow + 128) * DD;

  floatx4 acc[8][4];
#pragma unroll
  for (int i = 0; i < 8; i++)
#pragma unroll
    for (int j = 0; j < 4; j++)
      acc[i][j] = (floatx4){0.f, 0.f, 0.f, 0.f};

  GEMM256_LOOP();

  // epilogue: pair gate (bit3=0) with up (bit3=1) via shfl_xor 8, silu, write bf16 H
#pragma unroll
  for (int i = 0; i < 8; i++) {
    const int mb = m0 + wm + i * 16 + quad * 4;
#pragma unroll
    for (int j = 0; j < 4; j++) {
      const int nc = n0 + wn + j * 16 + r16;
      const int ng = ((nc >> 4) << 3) | (nc & 7);
#pragma unroll
      for (int r = 0; r < 4; r++) {
        const float v = acc[i][j][r];
        const float pv = __shfl_xor(v, 8);
        const float g = (lane & 8) ? pv : v;
        const float u = (lane & 8) ? v : pv;
        const float hv = g * u / (1.f + __expf(-g));
        const int m = mb + r;
        if (!(lane & 8) && m < cnt)
          H[(size_t)(off + m) * DD + ng] = f2bf(hv);
      }
    }
  }
}

// ---------------- grouped GEMM 2: Y[slot] = H[slot] @ Wd ----------------
__global__ __launch_bounds__(512, 2) void down_kernel(
    const u16* __restrict__ H, const u16* __restrict__ Wd,
    const int* __restrict__ counts, const int* __restrict__ offsets,
    u16* __restrict__ Y, int TK2) {
  const int e = blockIdx.z;
  const int cnt = counts[e];
  const int m0 = blockIdx.y * 256;
  if (m0 >= cnt) return;
  const int off = offsets[e];
  const int n0 = blockIdx.x * 256;

  __shared__ u16 As[4 * 8192];
  __shared__ u16 Bs[4 * 8192];

  const int t = threadIdx.x;
  const int lane = t & 63;
  const int wave = t >> 6;
  const int wm = (wave >> 2) * 128;
  const int wn = (wave & 3) * 64;
  const int r16 = lane & 15;
  const int quad = lane >> 4;
  const int swz = quad ^ ((r16 >> 1) & 3);
  const int offA = (wm + r16) * 32 + swz * 8;
  const int offB = (wn + r16) * 32 + swz * 8;

  const int drow = t >> 2;
  const int dpos = t & 3;
  const int c8 = (dpos ^ ((drow >> 1) & 3)) * 8;
  int r0 = off + m0 + drow;       if (r0 > TK2 - 1) r0 = TK2 - 1;
  int r1 = off + m0 + drow + 128; if (r1 > TK2 - 1) r1 = TK2 - 1;
  const u16* sA0 = H + (size_t)r0 * DD + c8;
  const u16* sA1 = H + (size_t)r1 * DD + c8;
  const u16* bbase = Wd + ((size_t)e * DD + n0) * DD + c8;
  const u16* sB0 = bbase + (size_t)drow * DD;
  const u16* sB1 = bbase + (size_t)(drow + 128) * DD;

  floatx4 acc[8][4];
#pragma unroll
  for (int i = 0; i < 8; i++)
#pragma unroll
    for (int j = 0; j < 4; j++)
      acc[i][j] = (floatx4){0.f, 0.f, 0.f, 0.f};

  GEMM256_LOOP();

#pragma unroll
  for (int i = 0; i < 8; i++) {
    const int mb = m0 + wm + i * 16 + quad * 4;
#pragma unroll
    for (int r = 0; r < 4; r++) {
      const int m = mb + r;
      if (m < cnt) {
        u16* yrow = Y + (size_t)(off + m) * DD + n0 + wn + r16;
#pragma unroll
        for (int j = 0; j < 4; j++)
          yrow[j * 16] = f2bf(acc[i][j][r]);
      }
    }
  }
}

#undef STAGE
#undef COMPUTE

// ---------------- combine: out[t] = w0*Y[s0] + w1*Y[s1] ----------------
__global__ __launch_bounds__(256) void combine_kernel(
    const u16* __restrict__ Y, const int2* __restrict__ slots,
    const float2* __restrict__ wts, float* __restrict__ out, int T) {
  const int wave = threadIdx.x >> 6;
  const int lane = threadIdx.x & 63;
  const int t = blockIdx.x * 4 + wave;
  if (t >= T) return;
  const int2 s = slots[t];
  const float2 w = wts[t];
  const uint4* y0 = (const uint4*)(Y + (size_t)s.x * DD);
  const uint4* y1 = (const uint4*)(Y + (size_t)s.y * DD);
  float4* o = (float4*)(out + (size_t)t * DD);
#pragma unroll
  for (int c = 0; c < 2; c++) {
    const int idx = lane + c * 64;          // 128 uint4 per row (8 bf16 each)
    const uint4 a = y0[idx];
    const uint4 b = y1[idx];
    const u32 au[4] = {a.x, a.y, a.z, a.w};
    const u32 bu[4] = {b.x, b.y, b.z, b.w};
    float4 r[2];
#pragma unroll
    for (int q = 0; q < 4; q++) {
      const float2 fa = bf2f2(au[q]);
      const float2 fb = bf2f2(bu[q]);
      ((float*)r)[q * 2]     = w.x * fa.x + w.y * fb.x;
      ((float*)r)[q * 2 + 1] = w.x * fa.y + w.y * fb.y;
    }
    o[idx * 2]     = r[0];
    o[idx * 2 + 1] = r[1];
  }
}

extern "C" void kernel_launch(void* const* d_in, const int* in_sizes, int n_in,
                              void* d_out, int out_size, void* d_ws, size_t ws_size,
                              hipStream_t stream) {
  const float* x  = (const float*)d_in[0];
  const float* rw = (const float*)d_in[1];
  const float* rb = (const float*)d_in[2];
  const float* wg = (const float*)d_in[3];
  const float* wu = (const float*)d_in[4];
  const float* wd = (const float*)d_in[5];
  float* out = (float*)d_out;
  const int T = in_sizes[0] / DD;       // 16384
  const int TK2 = 2 * T;

  // workspace carve. Y (64MB) aliases [Wgu(32MB) xbf(32MB)], which are dead after gateup.
  char* p = (char*)d_ws;
  int* ctrl = (int*)p; p += 256;        // [0..7]=counts [8..15]=cursors [16..23]=offsets
  int2* experts = (int2*)p;  p += (size_t)T * 8;
  float2* wtsp  = (float2*)p; p += (size_t)T * 8;
  int* tok_id   = (int*)p;   p += (size_t)TK2 * 4;
  int2* slots   = (int2*)p;  p += (size_t)T * 8;
  u16* Wd       = (u16*)p;   p += (size_t)NE * DD * DD * 2;
  u16* H        = (u16*)p;   p += (size_t)TK2 * DD * 2;
  u16* Wgu      = (u16*)p;   // 32 MB
  u16* xbf      = (u16*)(p + (size_t)NE * 2048 * DD * 2);  // 32 MB
  u16* Y        = (u16*)p;   // 64 MB, aliases Wgu+xbf
  p += (size_t)TK2 * DD * 2;
  if ((size_t)(p - (char*)d_ws) > ws_size) return;  // insufficient scratch -> visible failure

  hipMemsetAsync(ctrl, 0, 256, stream);

  router_kernel<<<T / 4, 256, 0, stream>>>(x, rw, rb, experts, wtsp, xbf, T);
  count_kernel<<<T / 256, 256, 0, stream>>>(experts, ctrl, T);
  offsets_kernel<<<1, 1, 0, stream>>>(ctrl, ctrl + 16);
  scatter_kernel<<<T / 256, 256, 0, stream>>>(experts, ctrl + 16, ctrl + 8, tok_id, slots, T);
  convert_kernel<<<dim3(16, 16, 24), 256, 0, stream>>>(wg, wu, wd, Wgu, Wd);
  gateup_kernel<<<dim3(8, (T + 255) / 256, NE), 512, 0, stream>>>(
      xbf, Wgu, tok_id, ctrl + 16, ctrl, H);
  down_kernel<<<dim3(4, (T + 255) / 256, NE), 512, 0, stream>>>(
      H, Wd, ctrl, ctrl + 16, Y, TK2);
  combine_kernel<<<T / 4, 256, 0, stream>>>(Y, slots, wtsp, out, T);
}

// Round 2
// 519.870 us; speedup vs baseline: 1.1309x; 1.1309x over previous
//
#include <hip/hip_runtime.h>
#include <hip/hip_bf16.h>
#include <cstdint>
#include <cstddef>

typedef unsigned short u16;
typedef unsigned int u32;
typedef __attribute__((ext_vector_type(8))) short short8;
typedef __attribute__((ext_vector_type(4))) float floatx4;

#define DD 1024
#define NE 8

// 16-byte async global->LDS copy (gfx950). LDS dest must be wave-uniform base + lane*16;
// global source address is per-lane (gather OK).
#define GLOAD_LDS16(G, L)                                               \
  __builtin_amdgcn_global_load_lds(                                     \
      (const __attribute__((address_space(1))) void*)(G),               \
      (__attribute__((address_space(3))) void*)(L), 16, 0, 0)

// LDS byte address (32-bit, ds-instruction space) of a __shared__ pointer.
#define LDSA(P) ((u32)(uintptr_t)(const __attribute__((address_space(3))) void*)(P))

// Inline-asm ds_read_b128: opaque to SIInsertWaitcnts' LDS-DMA hazard tracking,
// so in-flight global_load_lds stay in flight (counted vmcnt survives). Rule #18:
// consumer MFMAs are fenced by explicit lgkmcnt(0) + sched_barrier(0).
#define DSR(DST, ADDR, IMM)                                             \
  asm volatile("ds_read_b128 %0, %1 offset:" IMM : "=v"(DST) : "v"(ADDR))

__device__ __forceinline__ u16 f2bf(float f) {
  union { __hip_bfloat16 h; u16 u; } cv;
  cv.h = __float2bfloat16(f);
  return cv.u;
}

__device__ __forceinline__ float2 bf2f2(u32 u) {
  union { u32 v; float f; } lo, hi;
  lo.v = u << 16; hi.v = u & 0xffff0000u;
  float2 r; r.x = lo.f; r.y = hi.f; return r;
}

// ---------------- router: fp32 logits, top-2, softmax weights; emits x in bf16 ----------------
__global__ __launch_bounds__(256) void router_kernel(
    const float* __restrict__ x, const float* __restrict__ rw,
    const float* __restrict__ rb, int2* __restrict__ experts,
    float2* __restrict__ wts, u16* __restrict__ xbf, int T) {
  const int wave = threadIdx.x >> 6;
  const int lane = threadIdx.x & 63;
  const int t = blockIdx.x * 4 + wave;
  if (t >= T) return;
  const float* xr = x + (size_t)t * DD;
  float acc[NE] = {0.f, 0.f, 0.f, 0.f, 0.f, 0.f, 0.f, 0.f};
#pragma unroll
  for (int i = 0; i < 16; i++) {
    const int idx = lane + i * 64;
    const float xv = xr[idx];
    xbf[(size_t)t * DD + idx] = f2bf(xv);
    const float4* r4 = (const float4*)(rw + (size_t)idx * NE);
    float4 a = r4[0], b = r4[1];
    acc[0] += xv * a.x; acc[1] += xv * a.y; acc[2] += xv * a.z; acc[3] += xv * a.w;
    acc[4] += xv * b.x; acc[5] += xv * b.y; acc[6] += xv * b.z; acc[7] += xv * b.w;
  }
#pragma unroll
  for (int s = 1; s < 64; s <<= 1)
#pragma unroll
    for (int e = 0; e < NE; e++)
      acc[e] += __shfl_xor(acc[e], s);
  if (lane == 0) {
    float lg[NE];
#pragma unroll
    for (int e = 0; e < NE; e++) lg[e] = acc[e] + rb[e];
    float l0 = lg[0]; int i0 = 0;
#pragma unroll
    for (int e = 1; e < NE; e++) if (lg[e] > l0) { l0 = lg[e]; i0 = e; }
    float l1 = -3.4e38f; int i1 = 0;
#pragma unroll
    for (int e = 0; e < NE; e++) {
      if (e == i0) continue;
      if (lg[e] > l1) { l1 = lg[e]; i1 = e; }
    }
    const float w0 = 1.f / (1.f + expf(l1 - l0));
    experts[t] = make_int2(i0, i1);
    wts[t] = make_float2(w0, 1.f - w0);
  }
}

// ---------------- count tokens per expert ----------------
__global__ __launch_bounds__(256) void count_kernel(
    const int2* __restrict__ experts, int* __restrict__ counts, int T) {
  __shared__ int lc[NE];
  if (threadIdx.x < NE) lc[threadIdx.x] = 0;
  __syncthreads();
  const int t = blockIdx.x * 256 + threadIdx.x;
  if (t < T) {
    int2 e = experts[t];
    atomicAdd(&lc[e.x], 1);
    atomicAdd(&lc[e.y], 1);
  }
  __syncthreads();
  if (threadIdx.x < NE && lc[threadIdx.x] > 0)
    atomicAdd(&counts[threadIdx.x], lc[threadIdx.x]);
}

__global__ void offsets_kernel(const int* __restrict__ counts, int* __restrict__ offsets) {
  int s = 0;
  for (int e = 0; e < NE; e++) { offsets[e] = s; s += counts[e]; }
}

// ---------------- scatter: compact expert groups + inverse map (slots per token) ----------------
__global__ __launch_bounds__(256) void scatter_kernel(
    const int2* __restrict__ experts, const int* __restrict__ offsets,
    int* __restrict__ cursors, int* __restrict__ tok_id,
    int2* __restrict__ slots, int T) {
  __shared__ int lc[NE], lb[NE];
  if (threadIdx.x < NE) lc[threadIdx.x] = 0;
  __syncthreads();
  const int t = blockIdx.x * 256 + threadIdx.x;
  int2 e = make_int2(0, 0);
  int p0 = 0, p1 = 0;
  if (t < T) {
    e = experts[t];
    p0 = atomicAdd(&lc[e.x], 1);
    p1 = atomicAdd(&lc[e.y], 1);
  }
  __syncthreads();
  if (threadIdx.x < NE) lb[threadIdx.x] = atomicAdd(&cursors[threadIdx.x], lc[threadIdx.x]);
  __syncthreads();
  if (t < T) {
    const int s0 = offsets[e.x] + lb[e.x] + p0;
    const int s1 = offsets[e.y] + lb[e.y] + p1;
    tok_id[s0] = t;
    tok_id[s1] = t;
    slots[t] = make_int2(s0, s1);
  }
}

// ---------------- weight transpose + fp32->bf16 convert ----------------
// Wgu: [e][nc][k], nc = ((n>>3)<<4) | (which<<3) | (n&7); Wd: [e][n][k]
__global__ __launch_bounds__(256) void convert_kernel(
    const float* __restrict__ wg, const float* __restrict__ wu,
    const float* __restrict__ wd, u16* __restrict__ Wgu, u16* __restrict__ Wd) {
  const int z = blockIdx.z;        // mat*8 + e
  const int mat = z >> 3;
  const int e = z & 7;
  const float* src = (mat == 0 ? wg : (mat == 1 ? wu : wd)) + (size_t)e * DD * DD;
  __shared__ float tile[64][65];
  const int k0 = blockIdx.y * 64, n0 = blockIdx.x * 64;
  const int tx = threadIdx.x & 63, ty = threadIdx.x >> 6;
#pragma unroll
  for (int i = 0; i < 16; i++) {
    const int kk = i * 4 + ty;
    tile[kk][tx] = src[(size_t)(k0 + kk) * DD + n0 + tx];
  }
  __syncthreads();
#pragma unroll
  for (int i = 0; i < 16; i++) {
    const int nn = i * 4 + ty;
    const int n = n0 + nn;
    const u16 h = f2bf(tile[tx][nn]);   // = src[k0+tx][n]
    if (mat == 2) {
      Wd[((size_t)e * DD + n) * DD + k0 + tx] = h;
    } else {
      const int nc = ((n >> 3) << 4) | (mat << 3) | (n & 7);
      Wgu[((size_t)e * 2048 + nc) * DD + k0 + tx] = h;
    }
  }
}

// ======================================================================
// 256x256-tile grouped GEMM engine, BK=32, 8 waves, 4-deep LDS ring with
// counted vmcnt (T3+T4), XOR-swizzled LDS (T2), setprio around MFMA (T5).
//
// Ring discipline (per wave, 4 global_load_lds per tile):
//   prologue: issue L0,L1,L2; vmcnt(8) -> L0 done; barrier.
//   iter t (t<29): ds_read buf[t&3]; issue L(t+3) into buf[(t+3)&3]
//     (whose readers all left at the barrier ending iter t-1); lgkmcnt(0);
//     MFMA; vmcnt(8) -> own L(t+1) done; barrier -> ALL waves' L(t+1) done.
//   tail drains 4 -> 0. One barrier per tile; vmcnt never 0 in steady state.
// No "memory" clobbers in the hot loop; fragment loads are inline-asm
// ds_read_b128 so SIInsertWaitcnts' LDS-DMA hazard tracking cannot inject
// vmcnt(0) drains (the round-1 failure mode). Order pinned by sched_barrier(0).
// ======================================================================

// BUFOB = byte offset of the tile buffer; DO_STAGE/SBUF = prefetch control.
#define COMPUTE(BUFOB, DO_STAGE, SBUF)                                  \
  {                                                                     \
    short8 a[8], b[4];                                                  \
    const u32 ab_ = asb + (u32)(BUFOB) + offAB;                         \
    const u32 bb_ = bsb + (u32)(BUFOB) + offBB;                         \
    DSR(a[0], ab_, "0");    DSR(a[1], ab_, "1024");                     \
    DSR(a[2], ab_, "2048"); DSR(a[3], ab_, "3072");                     \
    DSR(a[4], ab_, "4096"); DSR(a[5], ab_, "5120");                     \
    DSR(a[6], ab_, "6144"); DSR(a[7], ab_, "7168");                     \
    DSR(b[0], bb_, "0");    DSR(b[1], bb_, "1024");                     \
    DSR(b[2], bb_, "2048"); DSR(b[3], bb_, "3072");                     \
    if (DO_STAGE) {                                                     \
      GLOAD_LDS16(sA0, &As[(SBUF) * 8192 + t * 8]);                     \
      GLOAD_LDS16(sA1, &As[(SBUF) * 8192 + 4096 + t * 8]);              \
      GLOAD_LDS16(sB0, &Bs[(SBUF) * 8192 + t * 8]);                     \
      GLOAD_LDS16(sB1, &Bs[(SBUF) * 8192 + 4096 + t * 8]);              \
      sA0 += 32; sA1 += 32; sB0 += 32; sB1 += 32;                       \
    }                                                                   \
    asm volatile("s_waitcnt lgkmcnt(0)");                               \
    __builtin_amdgcn_sched_barrier(0);                                  \
    __builtin_amdgcn_s_setprio(1);                                      \
    _Pragma("unroll")                                                   \
    for (int i = 0; i < 8; i++)                                         \
      _Pragma("unroll")                                                 \
      for (int j = 0; j < 4; j++)                                       \
        acc[i][j] = __builtin_amdgcn_mfma_f32_16x16x32_bf16(            \
            a[i], b[j], acc[i][j], 0, 0, 0);                            \
    __builtin_amdgcn_s_setprio(0);                                      \
    __builtin_amdgcn_sched_barrier(0);                                  \
  }

#define STAGE(BUF)                                                      \
  {                                                                     \
    GLOAD_LDS16(sA0, &As[(BUF) * 8192 + t * 8]);                        \
    GLOAD_LDS16(sA1, &As[(BUF) * 8192 + 4096 + t * 8]);                 \
    GLOAD_LDS16(sB0, &Bs[(BUF) * 8192 + t * 8]);                        \
    GLOAD_LDS16(sB1, &Bs[(BUF) * 8192 + 4096 + t * 8]);                 \
    sA0 += 32; sA1 += 32; sB0 += 32; sB1 += 32;                         \
  }

#define SYNC(VM)                                                        \
  __builtin_amdgcn_sched_barrier(0);                                    \
  asm volatile("s_waitcnt vmcnt(" VM ")");                              \
  __builtin_amdgcn_s_barrier();                                         \
  __builtin_amdgcn_sched_barrier(0);

#define GEMM256_LOOP()                                                  \
  STAGE(0); STAGE(1); STAGE(2);                                         \
  SYNC("8");                                                            \
  _Pragma("unroll 1")                                                   \
  for (int kt = 0; kt < 29; ++kt) {                                     \
    COMPUTE((kt & 3) * 16384, 1, (kt + 3) & 3);                         \
    SYNC("8");                                                          \
  }                                                                     \
  COMPUTE(1 * 16384, 0, 0);                                             \
  SYNC("4");                                                            \
  COMPUTE(2 * 16384, 0, 0);                                             \
  SYNC("0");                                                            \
  COMPUTE(3 * 16384, 0, 0);

// ---------------- grouped GEMM 1: H = silu(x@Wg)*(x@Wu) ----------------
__global__ __launch_bounds__(512, 2) void gateup_kernel(
    const u16* __restrict__ xbf, const u16* __restrict__ Wgu,
    const int* __restrict__ tok_id, const int* __restrict__ offsets,
    const int* __restrict__ counts, u16* __restrict__ H) {
  const int e = blockIdx.z;
  const int cnt = counts[e];
  const int m0 = blockIdx.y * 256;
  if (m0 >= cnt) return;
  const int off = offsets[e];
  const int n0 = blockIdx.x * 256;

  __shared__ u16 As[4 * 8192];   // 4 bufs x [256 rows][32 k], 64 KB
  __shared__ u16 Bs[4 * 8192];   // 64 KB

  const int t = threadIdx.x;     // 0..511
  const int lane = t & 63;
  const int wave = t >> 6;       // 0..7
  const int wm = (wave >> 2) * 128;   // 2 M-waves
  const int wn = (wave & 3) * 64;     // 4 N-waves
  const int r16 = lane & 15;
  const int quad = lane >> 4;
  // LDS row = 64B = 4x16B chunks; chunk stored at pos = chunk ^ ((row>>1)&3).
  // Read base rows (wm|wn + i*16 + r16): (row>>1)&3 == (r16>>1)&3 for all i.
  const int swz = quad ^ ((r16 >> 1) & 3);
  const u32 offAB = (u32)((wm + r16) * 64 + swz * 16);   // bytes
  const u32 offBB = (u32)((wn + r16) * 64 + swz * 16);
  const u32 asb = LDSA(&As[0]);
  const u32 bsb = LDSA(&Bs[0]);

  // staging: thread covers LDS rows (t>>2) and (t>>2)+128, chunk pos t&3.
  const int drow = t >> 2;
  const int dpos = t & 3;
  const int c8 = (dpos ^ ((drow >> 1) & 3)) * 8;   // same for row and row+128
  int r0 = m0 + drow;       if (r0 > cnt - 1) r0 = cnt - 1;
  int r1 = m0 + drow + 128; if (r1 > cnt - 1) r1 = cnt - 1;
  const u16* sA0 = xbf + (size_t)tok_id[off + r0] * DD + c8;
  const u16* sA1 = xbf + (size_t)tok_id[off + r1] * DD + c8;
  const u16* bbase = Wgu + ((size_t)e * 2048 + n0) * DD + c8;
  const u16* sB0 = bbase + (size_t)drow * DD;
  const u16* sB1 = bbase + (size_t)(drow + 128) * DD;

  floatx4 acc[8][4];
#pragma unroll
  for (int i = 0; i < 8; i++)
#pragma unroll
    for (int j = 0; j < 4; j++)
      acc[i][j] = (floatx4){0.f, 0.f, 0.f, 0.f};

  GEMM256_LOOP();

  // epilogue: pair gate (bit3=0) with up (bit3=1) via shfl_xor 8, silu, write bf16 H
#pragma unroll
  for (int i = 0; i < 8; i++) {
    const int mb = m0 + wm + i * 16 + quad * 4;
#pragma unroll
    for (int j = 0; j < 4; j++) {
      const int nc = n0 + wn + j * 16 + r16;
      const int ng = ((nc >> 4) << 3) | (nc & 7);
#pragma unroll
      for (int r = 0; r < 4; r++) {
        const float v = acc[i][j][r];
        const float pv = __shfl_xor(v, 8);
        const float g = (lane & 8) ? pv : v;
        const float u = (lane & 8) ? v : pv;
        const float hv = g * u / (1.f + __expf(-g));
        const int m = mb + r;
        if (!(lane & 8) && m < cnt)
          H[(size_t)(off + m) * DD + ng] = f2bf(hv);
      }
    }
  }
}

// ---------------- grouped GEMM 2: Y[slot] = H[slot] @ Wd ----------------
__global__ __launch_bounds__(512, 2) void down_kernel(
    const u16* __restrict__ H, const u16* __restrict__ Wd,
    const int* __restrict__ counts, const int* __restrict__ offsets,
    u16* __restrict__ Y, int TK2) {
  const int e = blockIdx.z;
  const int cnt = counts[e];
  const int m0 = blockIdx.y * 256;
  if (m0 >= cnt) return;
  const int off = offsets[e];
  const int n0 = blockIdx.x * 256;

  __shared__ u16 As[4 * 8192];
  __shared__ u16 Bs[4 * 8192];

  const int t = threadIdx.x;
  const int lane = t & 63;
  const int wave = t >> 6;
  const int wm = (wave >> 2) * 128;
  const int wn = (wave & 3) * 64;
  const int r16 = lane & 15;
  const int quad = lane >> 4;
  const int swz = quad ^ ((r16 >> 1) & 3);
  const u32 offAB = (u32)((wm + r16) * 64 + swz * 16);
  const u32 offBB = (u32)((wn + r16) * 64 + swz * 16);
  const u32 asb = LDSA(&As[0]);
  const u32 bsb = LDSA(&Bs[0]);

  const int drow = t >> 2;
  const int dpos = t & 3;
  const int c8 = (dpos ^ ((drow >> 1) & 3)) * 8;
  int r0 = off + m0 + drow;       if (r0 > TK2 - 1) r0 = TK2 - 1;
  int r1 = off + m0 + drow + 128; if (r1 > TK2 - 1) r1 = TK2 - 1;
  const u16* sA0 = H + (size_t)r0 * DD + c8;
  const u16* sA1 = H + (size_t)r1 * DD + c8;
  const u16* bbase = Wd + ((size_t)e * DD + n0) * DD + c8;
  const u16* sB0 = bbase + (size_t)drow * DD;
  const u16* sB1 = bbase + (size_t)(drow + 128) * DD;

  floatx4 acc[8][4];
#pragma unroll
  for (int i = 0; i < 8; i++)
#pragma unroll
    for (int j = 0; j < 4; j++)
      acc[i][j] = (floatx4){0.f, 0.f, 0.f, 0.f};

  GEMM256_LOOP();

#pragma unroll
  for (int i = 0; i < 8; i++) {
    const int mb = m0 + wm + i * 16 + quad * 4;
#pragma unroll
    for (int r = 0; r < 4; r++) {
      const int m = mb + r;
      if (m < cnt) {
        u16* yrow = Y + (size_t)(off + m) * DD + n0 + wn + r16;
#pragma unroll
        for (int j = 0; j < 4; j++)
          yrow[j * 16] = f2bf(acc[i][j][r]);
      }
    }
  }
}

#undef STAGE
#undef COMPUTE
#undef SYNC

// ---------------- combine: out[t] = w0*Y[s0] + w1*Y[s1] ----------------
__global__ __launch_bounds__(256) void combine_kernel(
    const u16* __restrict__ Y, const int2* __restrict__ slots,
    const float2* __restrict__ wts, float* __restrict__ out, int T) {
  const int wave = threadIdx.x >> 6;
  const int lane = threadIdx.x & 63;
  const int t = blockIdx.x * 4 + wave;
  if (t >= T) return;
  const int2 s = slots[t];
  const float2 w = wts[t];
  const uint4* y0 = (const uint4*)(Y + (size_t)s.x * DD);
  const uint4* y1 = (const uint4*)(Y + (size_t)s.y * DD);
  float4* o = (float4*)(out + (size_t)t * DD);
#pragma unroll
  for (int c = 0; c < 2; c++) {
    const int idx = lane + c * 64;          // 128 uint4 per row (8 bf16 each)
    const uint4 a = y0[idx];
    const uint4 b = y1[idx];
    const u32 au[4] = {a.x, a.y, a.z, a.w};
    const u32 bu[4] = {b.x, b.y, b.z, b.w};
    float4 r[2];
#pragma unroll
    for (int q = 0; q < 4; q++) {
      const float2 fa = bf2f2(au[q]);
      const float2 fb = bf2f2(bu[q]);
      ((float*)r)[q * 2]     = w.x * fa.x + w.y * fb.x;
      ((float*)r)[q * 2 + 1] = w.x * fa.y + w.y * fb.y;
    }
    o[idx * 2]     = r[0];
    o[idx * 2 + 1] = r[1];
  }
}

extern "C" void kernel_launch(void* const* d_in, const int* in_sizes, int n_in,
                              void* d_out, int out_size, void* d_ws, size_t ws_size,
                              hipStream_t stream) {
  const float* x  = (const float*)d_in[0];
  const float* rw = (const float*)d_in[1];
  const float* rb = (const float*)d_in[2];
  const float* wg = (const float*)d_in[3];
  const float* wu = (const float*)d_in[4];
  const float* wd = (const float*)d_in[5];
  float* out = (float*)d_out;
  const int T = in_sizes[0] / DD;       // 16384
  const int TK2 = 2 * T;

  // workspace carve. Y (64MB) aliases [Wgu(32MB) xbf(32MB)], which are dead after gateup.
  char* p = (char*)d_ws;
  int* ctrl = (int*)p; p += 256;        // [0..7]=counts [8..15]=cursors [16..23]=offsets
  int2* experts = (int2*)p;  p += (size_t)T * 8;
  float2* wtsp  = (float2*)p; p += (size_t)T * 8;
  int* tok_id   = (int*)p;   p += (size_t)TK2 * 4;
  int2* slots   = (int2*)p;  p += (size_t)T * 8;
  u16* Wd       = (u16*)p;   p += (size_t)NE * DD * DD * 2;
  u16* H        = (u16*)p;   p += (size_t)TK2 * DD * 2;
  u16* Wgu      = (u16*)p;   // 32 MB
  u16* xbf      = (u16*)(p + (size_t)NE * 2048 * DD * 2);  // 32 MB
  u16* Y        = (u16*)p;   // 64 MB, aliases Wgu+xbf
  p += (size_t)TK2 * DD * 2;
  if ((size_t)(p - (char*)d_ws) > ws_size) return;  // insufficient scratch -> visible failure

  hipMemsetAsync(ctrl, 0, 256, stream);

  router_kernel<<<T / 4, 256, 0, stream>>>(x, rw, rb, experts, wtsp, xbf, T);
  count_kernel<<<T / 256, 256, 0, stream>>>(experts, ctrl, T);
  offsets_kernel<<<1, 1, 0, stream>>>(ctrl, ctrl + 16);
  scatter_kernel<<<T / 256, 256, 0, stream>>>(experts, ctrl + 16, ctrl + 8, tok_id, slots, T);
  convert_kernel<<<dim3(16, 16, 24), 256, 0, stream>>>(wg, wu, wd, Wgu, Wd);
  gateup_kernel<<<dim3(8, (T + 255) / 256, NE), 512, 0, stream>>>(
      xbf, Wgu, tok_id, ctrl + 16, ctrl, H);
  down_kernel<<<dim3(4, (T + 255) / 256, NE), 512, 0, stream>>>(
      H, Wd, ctrl, ctrl + 16, Y, TK2);
  combine_kernel<<<T / 4, 256, 0, stream>>>(Y, slots, wtsp, out, T);
}